// Round 7
// baseline (841.533 us; speedup 1.0000x reference)
//
#include <hip/hip_runtime.h>
#include <cmath>

// ---------------------------------------------------------------------------
// Down_42468636623217 — round 9: ffn_k occupancy + barrier restructure.
//  r8 post-mortem: fusion right (FFN traffic 320->26.5 MB) but ffn_k = 109 us,
//  latency-bound: 17-barrier serial chain at 3 blocks/CU (LDS 48K) + a
//  256-block residency tail. This round: x1/x2 live in packed-bf16 REGISTERS
//  (same thread writes and reads them at identical fragment positions), gate
//  reuses the X buffer (dead after act GEMM) -> LDS 32K -> 4 blocks/CU,
//  exact one-round 1024-block grid; read-only GEMMs paired before barriers
//  -> 10 barriers (was 17). Rounding points unchanged.
// ---------------------------------------------------------------------------

#define EPI_NONE 0
#define EPI_EXP 5

typedef unsigned short u16;
typedef __bf16 v8bf __attribute__((ext_vector_type(8)));
typedef float f32x4 __attribute__((ext_vector_type(4)));

__device__ __forceinline__ float gelu_f(float v) {
  return 0.5f * v * (1.f + erff(v * 0.70710678118654752f));
}
__device__ __forceinline__ float sigmoid_f(float v) {
  return 1.f / (1.f + __expf(-v));
}
__device__ __forceinline__ float bf2f(u16 h) {
  return __uint_as_float((unsigned)h << 16);
}
__device__ __forceinline__ u16 f2bf(float f) {
  unsigned u = __float_as_uint(f);
  return (u16)((u + 0x7fffu + ((u >> 16) & 1u)) >> 16);
}
__device__ __forceinline__ unsigned f2bf_pk(float lo, float hi) {
  unsigned a = __float_as_uint(lo), b = __float_as_uint(hi);
  a = (a + 0x7fffu + ((a >> 16) & 1u)) >> 16;
  b = (b + 0x7fffu + ((b >> 16) & 1u)) >> 16;
  return a | (b << 16);
}
__device__ __forceinline__ void gld_lds16(const void* g, void* l) {
  __builtin_amdgcn_global_load_lds(
      (const __attribute__((address_space(1))) unsigned int*)g,
      (__attribute__((address_space(3))) unsigned int*)l, 16, 0, 0);
}

// --------------------------- DWT + transpose (r6 version) ------------------
__global__ __launch_bounds__(256) void pre_k(const float* __restrict__ x,
                                             u16* __restrict__ yL16,
                                             u16* __restrict__ yHHt16,
                                             u16* __restrict__ hllh16,
                                             u16* __restrict__ xpt) {
  int gx = blockIdx.x;  // 2 (jt) * 4 (ci tile) = 8
  int jt = gx & 1, cit = gx >> 1;
  int i = blockIdx.y, b = blockIdx.z;
  int j0 = jt * 32, ci0 = cit * 32;
  int tx = threadIdx.x & 31, ty = threadIdx.x >> 5;
  __shared__ float sll[32][33], shl[32][33], slh[32][33], shh[32][33];
  if (gx == 0) {
    int pl = 1 + ((threadIdx.x >> 7) << 1);  // planes 1,3: storage col 0
    long off = ((long)(b * 4 + pl) * 4160 + (long)i * 65) * 128 + (threadIdx.x & 127);
    xpt[off] = 0;
  } else if (gx == 1) {
    int pl = (threadIdx.x >> 7) << 1;        // planes 0,2: storage col 64
    long off = ((long)(b * 4 + pl) * 4160 + (long)i * 65 + 64) * 128 + (threadIdx.x & 127);
    xpt[off] = 0;
  }
  const float2* x2 = (const float2*)x;
#pragma unroll
  for (int k = 0; k < 4; ++k) {
    int ci = ty + 8 * k;
    long base = (((long)b * 128 + ci0 + ci) * 128 + 2 * i) * 64 + j0 + tx;
    float2 ab = x2[base];
    float2 cd = x2[base + 64];
    float a = ab.x, bb = ab.y, c = cd.x, d = cd.y;
    sll[ci][tx] = (a + bb + c + d) * 0.5f;
    shl[ci][tx] = (a - bb + c - d) * 0.5f;
    slh[ci][tx] = (a + bb - c - d) * 0.5f;
    shh[ci][tx] = (a - bb - c + d) * 0.5f;
  }
  __syncthreads();
  long tok = (long)b * 4096 + i * 64 + j0;
  int r = threadIdx.x >> 3;         // token col offset 0..31
  int q4 = (threadIdx.x & 7) << 2;  // channel offset 0,4,..,28
  float vll[4], vhl[4], vlh[4], vhh[4];
#pragma unroll
  for (int e = 0; e < 4; ++e) {
    vll[e] = sll[q4 + e][r];
    vhl[e] = shl[q4 + e][r];
    vlh[e] = slh[q4 + e][r];
    vhh[e] = shh[q4 + e][r];
  }
  uint2 u;
  u.x = f2bf_pk(vll[0], vll[1]);
  u.y = f2bf_pk(vll[2], vll[3]);
  *(uint2*)(yL16 + (tok + r) * 128 + ci0 + q4) = u;
  u.x = f2bf_pk(vhl[0], vhl[1]);
  u.y = f2bf_pk(vhl[2], vhl[3]);
  *(uint2*)(hllh16 + (tok + r) * 256 + ci0 + q4) = u;
  u.x = f2bf_pk(vlh[0], vlh[1]);
  u.y = f2bf_pk(vlh[2], vlh[3]);
  *(uint2*)(hllh16 + (tok + r) * 256 + 128 + ci0 + q4) = u;
  {
    int ch = threadIdx.x >> 3;        // channel offset 0..31
    int t4 = (threadIdx.x & 7) << 2;  // token offset 0,4,..,28
    uint2 h;
    h.x = f2bf_pk(shh[ch][t4], shh[ch][t4 + 1]);
    h.y = f2bf_pk(shh[ch][t4 + 2], shh[ch][t4 + 3]);
    *(uint2*)(yHHt16 + (long)(ci0 + ch) * 65536 + tok + t4) = h;
  }
  {
    long rb = (long)(b * 4) * 4160 + (long)i * 65;  // plane0 row base (x128)
    int ci = j0 + r;
    float pA[4], pB[4], pC[4], pD[4];
#pragma unroll
    for (int e = 0; e < 4; ++e) {
      pA[e] = 0.5f * (vll[e] + vhl[e] + vlh[e] + vhh[e]);
      pB[e] = 0.5f * (vll[e] - vhl[e] + vlh[e] - vhh[e]);
      pC[e] = 0.5f * (vll[e] + vhl[e] - vlh[e] - vhh[e]);
      pD[e] = 0.5f * (vll[e] - vhl[e] - vlh[e] + vhh[e]);
    }
    u.x = f2bf_pk(pA[0], pA[1]);
    u.y = f2bf_pk(pA[2], pA[3]);
    *(uint2*)(xpt + (rb + ci) * 128 + ci0 + q4) = u;
    u.x = f2bf_pk(pB[0], pB[1]);
    u.y = f2bf_pk(pB[2], pB[3]);
    *(uint2*)(xpt + (rb + 4160 + ci + 1) * 128 + ci0 + q4) = u;
    u.x = f2bf_pk(pC[0], pC[1]);
    u.y = f2bf_pk(pC[2], pC[3]);
    *(uint2*)(xpt + (rb + 8320 + ci) * 128 + ci0 + q4) = u;
    u.x = f2bf_pk(pD[0], pD[1]);
    u.y = f2bf_pk(pD[2], pD[3]);
    *(uint2*)(xpt + (rb + 12480 + ci + 1) * 128 + ci0 + q4) = u;
  }
}

// ---------------------- weights fp32 -> bf16 (one pass) --------------------
__global__ __launch_bounds__(256) void wcvt8_k(
    const float* __restrict__ a0, const float* __restrict__ a1,
    const float* __restrict__ a2, const float* __restrict__ a3,
    const float* __restrict__ a4, const float* __restrict__ a5,
    const float* __restrict__ a6, const float* __restrict__ a7,
    unsigned* __restrict__ dst, unsigned* __restrict__ zp) {
  if (blockIdx.x >= 768) {
    zp[(blockIdx.x - 768) * 256 + threadIdx.x] = 0;  // 17 blocks = 17408 B
    return;
  }
  int f = blockIdx.x * 256 + threadIdx.x;  // 196608 uints
  int e = 2 * f;
  if (e < 262144) {
    int ch = e >> 13, kg = (e >> 10) & 7, n = (e >> 3) & 127, ke = e & 7;
    int k = ch * 64 + kg * 8 + ke;
    int stg = ch >> 2, sub = ch & 3;
    int kwsel = sub >> 1, chalf = sub & 1;
    int kh = stg >> 1, cp = stg & 1;
    int kw = cp ? (kwsel ? 2 : 0) : (kwsel ? 3 : 1);
    int c = chalf * 64 + (k & 63);
    long si = (((long)n * 128 + c) * 4 + kh) * 4 + kw;
    dst[f] = f2bf_pk(a0[si], a0[si + 16]);  // k+1 -> c+1 -> +16 floats
    return;
  }
  const float* s; int b;
  if (e < 294912)      { s = a1; b = 262144; }
  else if (e < 311296) { s = a2; b = 294912; }
  else if (e < 327680) { s = a3; b = 311296; }
  else if (e < 344064) { s = a4; b = 327680; }
  else if (e < 360448) { s = a5; b = 344064; }
  else if (e < 376832) { s = a6; b = 360448; }
  else                 { s = a7; b = 376832; }
  dst[f] = f2bf_pk(s[e - b], s[e - b + 1]);
}

// --------------------------- unified bf16 GEMM -----------------------------
// (still used for: conv1 1x1, QK softmax-numerator, PV)
template <int AMODE, int EPI>
__global__ __launch_bounds__(256) void gemm16_k(
    const u16* __restrict__ A, long sA, int lda,
    const u16* __restrict__ B, long sB, int ldb,
    u16* __restrict__ C, long sC, int ldc,
    int K, float alpha, const float* __restrict__ bias,
    const u16* __restrict__ aux, const float* __restrict__ sc) {
  __shared__ __align__(16) char smem[32768];
  char* As = smem;
  char* Bs = smem + 16384;
  int z = blockIdx.z;
  int tid = threadIdx.x, lane = tid & 63, w = tid >> 6;
  int wm = w >> 1, wn = w & 1, l15 = lane & 15, l4 = lane >> 4;
  const u16* Ab = A + (long)z * sA + (long)blockIdx.x * 128 * lda;
  const u16* Bb = B + (long)z * sB + (long)blockIdx.y * 128 * ldb;
  const float* scz = (AMODE == 1) ? sc + (long)z * K : nullptr;
  int sm = tid >> 3, skg = tid & 7;
  int sbase = sm * 128 + ((skg ^ (sm & 7)) << 4);
  uint4 pa[4], pb[4];

  auto loadAB = [&](int k0) {
#pragma unroll
    for (int u = 0; u < 4; ++u) {
      pb[u] = *(const uint4*)(Bb + (long)(sm + 32 * u) * ldb + k0 + skg * 8);
      uint4 v = *(const uint4*)(Ab + (long)(sm + 32 * u) * lda + k0 + skg * 8);
      if (AMODE == 1) {
        float4 s0 = *(const float4*)(scz + k0 + skg * 8);
        float4 s1 = *(const float4*)(scz + k0 + skg * 8 + 4);
        v.x = f2bf_pk(bf2f((u16)(v.x & 0xffff)) * s0.x, bf2f((u16)(v.x >> 16)) * s0.y);
        v.y = f2bf_pk(bf2f((u16)(v.y & 0xffff)) * s0.z, bf2f((u16)(v.y >> 16)) * s0.w);
        v.z = f2bf_pk(bf2f((u16)(v.z & 0xffff)) * s1.x, bf2f((u16)(v.z >> 16)) * s1.y);
        v.w = f2bf_pk(bf2f((u16)(v.w & 0xffff)) * s1.z, bf2f((u16)(v.w >> 16)) * s1.w);
      }
      pa[u] = v;
    }
  };

  f32x4 acc[4][4] = {};
  loadAB(0);
  int nch = K >> 6;
  for (int ch = 0; ch < nch; ++ch) {
    __syncthreads();
#pragma unroll
    for (int u = 0; u < 4; ++u) {
      *(uint4*)(As + sbase + u * 4096) = pa[u];
      *(uint4*)(Bs + sbase + u * 4096) = pb[u];
    }
    __syncthreads();
    if (ch + 1 < nch) loadAB((ch + 1) << 6);
#pragma unroll
    for (int s = 0; s < 2; ++s) {
      int ko = (((s << 2) | l4) ^ (l15 & 7)) << 4;
      v8bf af[4], bfr[4];
#pragma unroll
      for (int t = 0; t < 4; ++t) {
        af[t] = *(const v8bf*)(As + (64 * wm + 16 * t + l15) * 128 + ko);
        bfr[t] = *(const v8bf*)(Bs + (64 * wn + 16 * t + l15) * 128 + ko);
      }
#pragma unroll
      for (int mt = 0; mt < 4; ++mt)
#pragma unroll
        for (int nt = 0; nt < 4; ++nt)
          acc[mt][nt] = __builtin_amdgcn_mfma_f32_16x16x32_bf16(af[mt], bfr[nt], acc[mt][nt], 0, 0, 0);
    }
  }
  u16* Cb = C + (long)z * sC;
#pragma unroll
  for (int mt = 0; mt < 4; ++mt) {
#pragma unroll
    for (int nt = 0; nt < 4; ++nt) {
      f32x4 a = acc[mt][nt];
      int n = blockIdx.y * 128 + 64 * wn + 16 * nt + l15;
      float bv = bias ? bias[n] : 0.f;
#pragma unroll
      for (int r = 0; r < 4; ++r) {
        long m = (long)blockIdx.x * 128 + 64 * wm + 16 * mt + 4 * l4 + r;
        float v = a[r] * alpha + bv;
        if (EPI == EPI_EXP) v = __expf(v);
        Cb[m * ldc + n] = f2bf(v);
      }
    }
  }
}

// --------------------------- fused FFN -------------------------------------
// Per 64-token tile (1024 blocks = exactly 4/CU):
//  e1 = gelu(ln1(X)@fc1)        [REGISTERS, packed bf16]
//  A  = gelu(X@div) - e1        [LDS]
//  e2 = gelu(A@fc2)             [REGISTERS]
//  A  = ln3(X); A = gelu(A@fc3a); A = A@fc3b + e2
//  gate = sigmoid(X@act) -> X buffer (X dead after act GEMM)
//  out = lnn(A) * gate.
// Register e-values are written and read by the SAME thread at identical
// fragment (m,n) positions. LDS: X + A = 32 KB. 10 barriers (was 17).
__global__ __launch_bounds__(256) __attribute__((amdgpu_waves_per_eu(4)))
void ffn_k(
    const u16* __restrict__ Xg,
    const u16* __restrict__ w_fc1, const u16* __restrict__ w_div,
    const u16* __restrict__ w_fc2, const u16* __restrict__ w_fc3a,
    const u16* __restrict__ w_fc3b, const u16* __restrict__ w_act,
    const float* __restrict__ b_fc1, const float* __restrict__ b_div,
    const float* __restrict__ b_fc2, const float* __restrict__ b_fc3a,
    const float* __restrict__ b_fc3b, const float* __restrict__ b_act,
    const float* __restrict__ ln1g, const float* __restrict__ ln1b,
    const float* __restrict__ ln3g, const float* __restrict__ ln3b,
    const float* __restrict__ lnng, const float* __restrict__ lnnb,
    u16* __restrict__ out) {
  __shared__ __align__(16) char smem[32768];
  char* X = smem;
  char* A = smem + 16384;
  int z = blockIdx.x;
  long t0 = (long)z * 64;
  int tid = threadIdx.x, lane = tid & 63, w = tid >> 6;
  int wm = w >> 1, wn = w & 1, l15 = lane & 15, l4 = lane >> 4;

  // stage X with pre-swizzled global source (LDS dest linear; m173 pattern)
  {
    const u16* src = Xg + t0 * 128;
#pragma unroll
    for (int r = 0; r < 4; ++r) {
      int u = r * 256 + tid;
      int row = u >> 4, cg = u & 15;
      gld_lds16(src + row * 128 + ((cg ^ (row & 7)) << 3),
                X + (r * 256 + w * 64) * 16);
    }
  }

  // GEMM: acc = Asrc(64x128, swizzled LDS) @ Bg(128x128 N-major)^T
  auto gemm = [&](const char* Asrc, const u16* Bg, f32x4 (&acc)[2][4]) {
#pragma unroll
    for (int mt = 0; mt < 2; ++mt)
#pragma unroll
      for (int nt = 0; nt < 4; ++nt) acc[mt][nt] = f32x4{0.f, 0.f, 0.f, 0.f};
#pragma unroll
    for (int s = 0; s < 4; ++s) {
      v8bf af[2], bw[4];
#pragma unroll
      for (int mt = 0; mt < 2; ++mt) {
        int row = 32 * wm + 16 * mt + l15;
        af[mt] = *(const v8bf*)(Asrc + row * 256 + (((s * 4 + l4) ^ (row & 7)) << 4));
      }
#pragma unroll
      for (int nt = 0; nt < 4; ++nt) {
        int rn = 64 * wn + 16 * nt + l15;
        bw[nt] = *(const v8bf*)(Bg + rn * 128 + (s * 4 + l4) * 8);
      }
#pragma unroll
      for (int mt = 0; mt < 2; ++mt)
#pragma unroll
        for (int nt = 0; nt < 4; ++nt)
          acc[mt][nt] = __builtin_amdgcn_mfma_f32_16x16x32_bf16(
              af[mt], bw[nt], acc[mt][nt], 0, 0, 0);
    }
  };

  // register epilogue: er[nt*4 + mt*2 + rp] = packed bf16 pair (r=2rp,2rp+1)
  // mode 0 = gelu, 1 = sigmoid
  auto epi_reg = [&](f32x4 (&acc)[2][4], const float* bias,
                     unsigned (&er)[16], int mode) {
#pragma unroll
    for (int nt = 0; nt < 4; ++nt) {
      float bv = bias[64 * wn + 16 * nt + l15];
#pragma unroll
      for (int mt = 0; mt < 2; ++mt) {
#pragma unroll
        for (int rp = 0; rp < 2; ++rp) {
          float v0 = acc[mt][nt][2 * rp] + bv;
          float v1 = acc[mt][nt][2 * rp + 1] + bv;
          if (mode == 0) { v0 = gelu_f(v0); v1 = gelu_f(v1); }
          else           { v0 = sigmoid_f(v0); v1 = sigmoid_f(v1); }
          er[nt * 4 + mt * 2 + rp] = f2bf_pk(v0, v1);
        }
      }
    }
  };

  // LDS epilogue: mode 0 = gelu(v) - er, 1 = gelu(v), 2 = v + er
  auto epi_lds = [&](f32x4 (&acc)[2][4], const float* bias, char* dst,
                     const unsigned (&er)[16], int mode) {
#pragma unroll
    for (int nt = 0; nt < 4; ++nt) {
      int n = 64 * wn + 16 * nt + l15;
      float bv = bias[n];
#pragma unroll
      for (int mt = 0; mt < 2; ++mt) {
#pragma unroll
        for (int r = 0; r < 4; ++r) {
          int m = 32 * wm + 16 * mt + 4 * l4 + r;
          int off = m * 256 + (((n >> 3) ^ (m & 7)) << 4) + (n & 7) * 2;
          float ev = bf2f((u16)(er[nt * 4 + mt * 2 + (r >> 1)] >> (16 * (r & 1))));
          float v = acc[mt][nt][r] + bv;
          if (mode == 0) v = gelu_f(v) - ev;
          else if (mode == 1) v = gelu_f(v);
          else v += ev;
          *(u16*)(dst + off) = f2bf(v);
        }
      }
    }
  };

  // write packed-register values (epi layout) to LDS
  auto reg_to_lds = [&](const unsigned (&er)[16], char* dst) {
#pragma unroll
    for (int nt = 0; nt < 4; ++nt) {
      int n = 64 * wn + 16 * nt + l15;
#pragma unroll
      for (int mt = 0; mt < 2; ++mt) {
#pragma unroll
        for (int r = 0; r < 4; ++r) {
          int m = 32 * wm + 16 * mt + 4 * l4 + r;
          int off = m * 256 + (((n >> 3) ^ (m & 7)) << 4) + (n & 7) * 2;
          *(u16*)(dst + off) =
              (u16)(er[nt * 4 + mt * 2 + (r >> 1)] >> (16 * (r & 1)));
        }
      }
    }
  };

  // layernorm pass: src (bf16, swizzled LDS) -> dst; 16 rows/wave, 4 lanes/row
  auto lnpass = [&](const char* src, char* dst, const float* g,
                    const float* bt) {
    int row = w * 16 + (lane >> 2), q = lane & 3;
    float v[32];
    float s = 0.f, sq = 0.f;
#pragma unroll
    for (int gi = 0; gi < 4; ++gi) {
      int gr = q * 4 + gi;
      v8bf hv = *(const v8bf*)(src + row * 256 + ((gr ^ (row & 7)) << 4));
#pragma unroll
      for (int e = 0; e < 8; ++e) {
        float f = bf2f(((const u16*)&hv)[e]);
        v[gi * 8 + e] = f;
        s += f;
        sq += f * f;
      }
    }
    s += __shfl_xor(s, 1); sq += __shfl_xor(sq, 1);
    s += __shfl_xor(s, 2); sq += __shfl_xor(sq, 2);
    float mean = s * 0.0078125f;
    float rstd = rsqrtf(sq * 0.0078125f - mean * mean + 1e-5f);
#pragma unroll
    for (int gi = 0; gi < 4; ++gi) {
      int gr = q * 4 + gi;
      int c0 = gr * 8;
      unsigned o[4];
#pragma unroll
      for (int e = 0; e < 4; ++e) {
        float y0 = (v[gi * 8 + 2 * e] - mean) * rstd * g[c0 + 2 * e] + bt[c0 + 2 * e];
        float y1 = (v[gi * 8 + 2 * e + 1] - mean) * rstd * g[c0 + 2 * e + 1] + bt[c0 + 2 * e + 1];
        o[e] = f2bf_pk(y0, y1);
      }
      *(uint4*)(dst + row * 256 + ((gr ^ (row & 7)) << 4)) = *(uint4*)o;
    }
  };

  f32x4 acc[2][4];
  unsigned e1[16], e2[16], sg[16];
  __syncthreads();                               // b1: X staged (drains DMA)
  lnpass(X, A, ln1g, ln1b);
  __syncthreads();                               // b2: A = ln1(X)
  gemm(A, w_fc1, acc);
  epi_reg(acc, b_fc1, e1, 0);                    // e1 = x1 (regs)
  gemm(X, w_div, acc);
  __syncthreads();                               // b3: fc1 reads of A done
  epi_lds(acc, b_div, A, e1, 0);                 // A = gelu(X@div) - x1
  __syncthreads();                               // b4
  gemm(A, w_fc2, acc);
  epi_reg(acc, b_fc2, e2, 0);                    // e2 = x2 (regs)
  __syncthreads();                               // b5: fc2 reads of A done
  lnpass(X, A, ln3g, ln3b);
  __syncthreads();                               // b6: A = ln3(X)
  gemm(A, w_fc3a, acc);
  __syncthreads();                               // b7: fc3a reads done
  epi_lds(acc, b_fc3a, A, e1, 1);                // A = h = gelu(.)
  __syncthreads();                               // b8
  gemm(X, w_act, acc);
  epi_reg(acc, b_act, sg, 1);                    // sg = gate (regs)
  gemm(A, w_fc3b, acc);
  __syncthreads();                               // b9: reads of A and X done
  epi_lds(acc, b_fc3b, A, e2, 2);                // A = x2 + x3
  reg_to_lds(sg, X);                             // X = gate
  __syncthreads();                               // b10

  // final: out = lnn(A) * gate(X), written straight to global
  {
    int row = w * 16 + (lane >> 2), q = lane & 3;
    float v[32];
    float s = 0.f, sq = 0.f;
#pragma unroll
    for (int gi = 0; gi < 4; ++gi) {
      int gr = q * 4 + gi;
      v8bf hv = *(const v8bf*)(A + row * 256 + ((gr ^ (row & 7)) << 4));
#pragma unroll
      for (int e = 0; e < 8; ++e) {
        float f = bf2f(((const u16*)&hv)[e]);
        v[gi * 8 + e] = f;
        s += f;
        sq += f * f;
      }
    }
    s += __shfl_xor(s, 1); sq += __shfl_xor(sq, 1);
    s += __shfl_xor(s, 2); sq += __shfl_xor(sq, 2);
    float mean = s * 0.0078125f;
    float rstd = rsqrtf(sq * 0.0078125f - mean * mean + 1e-5f);
    u16* og = out + (t0 + row) * 128;
#pragma unroll
    for (int gi = 0; gi < 4; ++gi) {
      int gr = q * 4 + gi;
      int c0 = gr * 8;
      v8bf gv = *(const v8bf*)(X + row * 256 + ((gr ^ (row & 7)) << 4));
      unsigned o[4];
#pragma unroll
      for (int e = 0; e < 4; ++e) {
        float y0 = ((v[gi * 8 + 2 * e] - mean) * rstd * lnng[c0 + 2 * e] + lnnb[c0 + 2 * e]) *
                   bf2f(((const u16*)&gv)[2 * e]);
        float y1 = ((v[gi * 8 + 2 * e + 1] - mean) * rstd * lnng[c0 + 2 * e + 1] + lnnb[c0 + 2 * e + 1]) *
                   bf2f(((const u16*)&gv)[2 * e + 1]);
        o[e] = f2bf_pk(y0, y1);
      }
      *(uint4*)(og + c0) = *(uint4*)o;
    }
  }
}

// ------------- conv 4x4 s2 p1: polyphase implicit GEMM (bf16) --------------
__global__ __launch_bounds__(256) __attribute__((amdgpu_waves_per_eu(4)))
void conv4g_k(const u16* __restrict__ xpt, const u16* __restrict__ wb,
              const float* __restrict__ bias, const u16* __restrict__ zp,
              u16* __restrict__ dw16) {
  __shared__ __align__(16) char smem[33280];  // 2 x 16640 A buffers
  char* As = smem;
  int raw = blockIdx.x;
  int swz = (raw & 7) * 128 + (raw >> 3);
  int oi = swz & 63, b = swz >> 6;
  int tid = threadIdx.x, lane = tid & 63, w = tid >> 6;
  int wm = w >> 1, wn = w & 1, l15 = lane & 15, l4 = lane >> 4;
  f32x4 acc[2][4] = {};

  auto issueA = [&](int stg2, int bsel) {
    int kh = stg2 >> 1, cp2 = stg2 & 1;
    int roff = (kh == 0) ? -1 : (kh == 3) ? 1 : 0;
    int ri = oi + roff;
    int ph = (((kh + 1) & 1) << 1) | cp2;
    const u16* rowb = ((unsigned)ri < 64u)
        ? xpt + ((long)(b * 4 + ph) * 4160 + (long)ri * 65) * 128
        : zp;
    char* lb = As + bsel * 16640 + w * 1024;
#pragma unroll
    for (int i = 0; i < 4; ++i) {
      int d = i * 4096 + w * 1024 + lane * 16;
      int slot = d >> 8, cg = (d >> 4) & 15;
      gld_lds16(rowb + slot * 128 + ((cg ^ ((slot - cp2) & 7)) << 3),
                lb + i * 4096);
    }
    if (tid < 16) {
      gld_lds16(rowb + 64 * 128 + ((lane ^ ((64 - cp2) & 7)) << 3),
                As + bsel * 16640 + 16384);
    }
  };

  issueA(0, 0);
  for (int stg = 0; stg < 8; ++stg) {
    __syncthreads();
    if (stg < 7) issueA(stg + 1, (stg + 1) & 1);
    const char* Ab = As + (stg & 1) * 16640;
    int cp2 = stg & 1;
#pragma unroll
    for (int sub = 0; sub < 4; ++sub) {
      int chunk = stg * 4 + sub;
      const int kwsel = sub >> 1, chalf = sub & 1;
#pragma unroll
      for (int s = 0; s < 2; ++s) {
        v8bf bw[4], af[2];
#pragma unroll
        for (int nt = 0; nt < 4; ++nt) {
          int row = 64 * wn + 16 * nt + l15;
          bw[nt] = *(const v8bf*)(wb + ((long)(chunk * 8 + s * 4 + l4) * 128 + row) * 8);
        }
#pragma unroll
        for (int mt = 0; mt < 2; ++mt) {
          int slot = 32 * wm + 16 * mt + l15 + kwsel;
          int cg = chalf * 8 + s * 4 + l4;
          af[mt] = *(const v8bf*)(Ab + slot * 256 + ((cg ^ ((slot - cp2) & 7)) << 4));
        }
#pragma unroll
        for (int mt = 0; mt < 2; ++mt)
#pragma unroll
          for (int nt = 0; nt < 4; ++nt)
            acc[mt][nt] = __builtin_amdgcn_mfma_f32_16x16x32_bf16(
                af[mt], bw[nt], acc[mt][nt], 0, 0, 0);
      }
    }
  }
  __syncthreads();
  float* buf = (float*)(smem + w * 2176);  // 16 x 34 f32 per wave
  long obase = ((long)b * 128) * 4096 + oi * 64;
#pragma unroll
  for (int cg = 0; cg < 4; ++cg) {
    int co = 64 * wn + 16 * cg + l15;
    float bv = bias[co];
#pragma unroll
    for (int mt = 0; mt < 2; ++mt) {
      f32x4 a = acc[mt][cg];
#pragma unroll
      for (int r = 0; r < 4; ++r)
        buf[l15 * 34 + 16 * mt + 4 * l4 + r] = fmaxf(a[r] + bv, 0.f);
    }
    __syncthreads();
#pragma unroll
    for (int it = 0; it < 8; ++it) {
      int row = it * 2 + (lane >> 5);
      int mcol = lane & 31;
      int coz = 64 * wn + 16 * cg + row;
      dw16[obase + (long)coz * 4096 + 32 * wm + mcol] = f2bf(buf[row * 34 + mcol]);
    }
    __syncthreads();
  }
}

// --------------- attention column normalizer: sc = 1/sum_q E ---------------
__global__ __launch_bounds__(256) void ssum_k(const u16* __restrict__ E,
                                              float* __restrict__ sc) {
  int z = blockIdx.y;
  int k = blockIdx.x * 256 + threadIdx.x;
  const u16* Eb = E + (long)z * 262144 + k;
  float s = 0.f;
#pragma unroll 8
  for (int q = 0; q < 512; ++q) s += bf2f(Eb[(long)q * 512]);
  sc[(long)z * 512 + k] = 1.f / s;
}

// ------------------------------ combine ------------------------------------
__global__ __launch_bounds__(256) void combine_k(const u16* __restrict__ attf,
                                                 const u16* __restrict__ yt,
                                                 const u16* __restrict__ dw16,
                                                 const float* __restrict__ x,
                                                 float* __restrict__ out) {
  int gx = blockIdx.x;  // 2 (jt) * 4 (cot) = 8
  int jt = gx & 1, cot = gx >> 1;
  int i = blockIdx.y, b = blockIdx.z;
  int j0 = jt * 32, co0 = cot * 32;
  int tx = threadIdx.x & 31, ty = threadIdx.x >> 5;
  __shared__ float sa[32][33], sy[32][33];
  long tokbase = (long)b * 4096 + i * 64 + j0;
#pragma unroll
  for (int k = 0; k < 4; ++k) {
    int row = ty + 8 * k;
    long idx = (tokbase + row) * 128 + co0 + tx;
    sa[row][tx] = bf2f(attf[idx]);
    sy[row][tx] = bf2f(yt[idx]);
  }
  __syncthreads();
  float py = (float)(i * 127) / 63.0f;
  int y0 = (int)py;
  int y1 = min(y0 + 1, 127);
  float wy = py - (float)y0;
  int j = j0 + tx;
  float px = (float)(j * 127) / 63.0f;
  int x0 = (int)px;
  int x1 = min(x0 + 1, 127);
  float wx = px - (float)x0;
#pragma unroll
  for (int k = 0; k < 4; ++k) {
    int co = co0 + ty + 8 * k;
    const float* xb = x + (((long)b * 128 + co) * 128) * 128;
    float r0 = xb[y0 * 128 + x0] * (1.f - wx) + xb[y0 * 128 + x1] * wx;
    float r1 = xb[y1 * 128 + x0] * (1.f - wx) + xb[y1 * 128 + x1] * wx;
    float d2 = r0 * (1.f - wy) + r1 * wy;
    long oidx = (((long)b * 128 + co) * 64 + i) * 64 + j;
    float dwv = bf2f(dw16[oidx]);
    out[oidx] = sa[tx][ty + 8 * k] * (d2 - dwv) + sy[tx][ty + 8 * k];
  }
}

// ---------------------------------------------------------------------------
extern "C" void kernel_launch(void* const* d_in, const int* in_sizes, int n_in,
                              void* d_out, int out_size, void* d_ws, size_t ws_size,
                              hipStream_t stream) {
  const float* x = (const float*)d_in[0];
  const float* w1 = (const float*)d_in[1];
  const float* b1 = (const float*)d_in[2];
  const float* l1w = (const float*)d_in[3];
  const float* l1b = (const float*)d_in[4];
  const float* ln1g = (const float*)d_in[5];
  const float* ln1b = (const float*)d_in[6];
  const float* fc1w = (const float*)d_in[7];
  const float* fc1b = (const float*)d_in[8];
  const float* divw = (const float*)d_in[9];
  const float* divb = (const float*)d_in[10];
  const float* fc2w = (const float*)d_in[11];
  const float* fc2b = (const float*)d_in[12];
  const float* ln3g = (const float*)d_in[13];
  const float* ln3b = (const float*)d_in[14];
  const float* fc3aw = (const float*)d_in[15];
  const float* fc3ab = (const float*)d_in[16];
  const float* fc3bw = (const float*)d_in[17];
  const float* fc3bb = (const float*)d_in[18];
  const float* lnng = (const float*)d_in[19];
  const float* lnnb = (const float*)d_in[20];
  const float* actw = (const float*)d_in[21];
  const float* actb = (const float*)d_in[22];

  char* W = (char*)d_ws;
  u16* yL16 = (u16*)(W);
  u16* hllh16 = (u16*)(W + 16777216L);
  u16* yHHt16 = (u16*)(W + 50331648L);
  u16* y16 = (u16*)(W + 67108864L);
  u16* S16 = (u16*)(W + 83886080L);
  u16* attO16 = (u16*)(W + 150994944L);
  u16* dw16 = (u16*)(W + 167772160L);
  u16* t2 = (u16*)(W + 201326592L);
  float* sc = (float*)(W + 251658240L);
  u16* wall = (u16*)(W + 251920384L);
  u16* l1wb = wall;
  u16* w1b = wall + 262144;
  u16* fc1b16 = wall + 294912;
  u16* divb16 = wall + 311296;
  u16* fc2b16 = wall + 327680;
  u16* fc3ab16 = wall + 344064;
  u16* fc3bb16 = wall + 360448;
  u16* actb16 = wall + 376832;
  u16* xpt16 = S16;  // polyphase planes live in S16 region until QK GEMM
  u16* zp16 = (u16*)(W + 152043520L);  // 17408-B zero page (row-OOB reads)

  dim3 blk(256);
  const float qk_scale = 0.35355339059327373f;  // 8^-0.5

  wcvt8_k<<<dim3(785), blk, 0, stream>>>(l1w, w1, fc1w, divw, fc2w, fc3aw,
                                         fc3bw, actw, (unsigned*)wall,
                                         (unsigned*)zp16);
  // 1. DWT + transpose (bf16 outputs incl. yHH^T and padded polyphase planes)
  pre_k<<<dim3(8, 64, 16), blk, 0, stream>>>(x, yL16, yHHt16, hllh16, xpt16);
  // 2. conv1 (1x1, 256->128): y16 = hllh @ w1^T + b1
  gemm16_k<0, EPI_NONE><<<dim3(512, 1, 1), blk, 0, stream>>>(
      hllh16, 0, 256, w1b, 0, 256, y16, 0, 128, 256, 1.f, b1, nullptr, nullptr);
  // 3. conv4x4 stride2 + relu (DMA-staged polyphase implicit GEMM)
  conv4g_k<<<dim3(1024), blk, 0, stream>>>(xpt16, l1wb, l1b, zp16, dw16);
  // 4. E = exp(scale * yL @ y^T)  (softmax numerator; overwrites xpt region)
  gemm16_k<0, EPI_EXP><<<dim3(4, 4, 128), blk, 0, stream>>>(
      yL16, 65536, 128, y16, 65536, 128, S16, 262144, 512, 128, qk_scale,
      nullptr, nullptr, nullptr);
  // 5. sc_k = 1 / sum_q E
  ssum_k<<<dim3(2, 128), blk, 0, stream>>>(S16, sc);
  // 6. attO = (E * sc) @ yHH   (scale folded into A-loader, B = yHH^T rows)
  gemm16_k<1, EPI_NONE><<<dim3(4, 1, 128), blk, 0, stream>>>(
      S16, 262144, 512, yHHt16, 512, 65536, attO16, 65536, 128, 512, 1.f,
      nullptr, nullptr, sc);
  // 7. fused FFN: attO -> t2
  ffn_k<<<dim3(1024), blk, 0, stream>>>(
      attO16, fc1b16, divb16, fc2b16, fc3ab16, fc3bb16, actb16,
      fc1b, divb, fc2b, fc3ab, fc3bb, actb,
      ln1g, ln1b, ln3g, ln3b, lnng, lnnb, t2);
  // 8. combine: out = attf * (resize(x) - dw) + y
  combine_k<<<dim3(8, 64, 16), blk, 0, stream>>>(t2, y16, dw16, x, (float*)d_out);
}

// Round 9
// 765.166 us; speedup vs baseline: 1.0998x; 1.0998x over previous
//
#include <hip/hip_runtime.h>
#include <cmath>

// ---------------------------------------------------------------------------
// Down_42468636623217 — round 11: resubmit r10 (container infra failure).
//  r10 was never measured ("MI355X container failed twice"). Identical
//  source: ffn_k without the waves_per_eu attribute (r9 lesson: it is a
//  MINIMUM — allocator went to 8 waves/EU = 64 VGPRs and spilled the
//  e-register scheme). 128 VGPR -> 4 blocks/CU, LDS 32 KB, 10 barriers,
//  1024-block one-round grid.
// ---------------------------------------------------------------------------

#define EPI_NONE 0
#define EPI_EXP 5

typedef unsigned short u16;
typedef __bf16 v8bf __attribute__((ext_vector_type(8)));
typedef float f32x4 __attribute__((ext_vector_type(4)));

__device__ __forceinline__ float gelu_f(float v) {
  return 0.5f * v * (1.f + erff(v * 0.70710678118654752f));
}
__device__ __forceinline__ float sigmoid_f(float v) {
  return 1.f / (1.f + __expf(-v));
}
__device__ __forceinline__ float bf2f(u16 h) {
  return __uint_as_float((unsigned)h << 16);
}
__device__ __forceinline__ u16 f2bf(float f) {
  unsigned u = __float_as_uint(f);
  return (u16)((u + 0x7fffu + ((u >> 16) & 1u)) >> 16);
}
__device__ __forceinline__ unsigned f2bf_pk(float lo, float hi) {
  unsigned a = __float_as_uint(lo), b = __float_as_uint(hi);
  a = (a + 0x7fffu + ((a >> 16) & 1u)) >> 16;
  b = (b + 0x7fffu + ((b >> 16) & 1u)) >> 16;
  return a | (b << 16);
}
__device__ __forceinline__ void gld_lds16(const void* g, void* l) {
  __builtin_amdgcn_global_load_lds(
      (const __attribute__((address_space(1))) unsigned int*)g,
      (__attribute__((address_space(3))) unsigned int*)l, 16, 0, 0);
}

// --------------------------- DWT + transpose (r6 version) ------------------
__global__ __launch_bounds__(256) void pre_k(const float* __restrict__ x,
                                             u16* __restrict__ yL16,
                                             u16* __restrict__ yHHt16,
                                             u16* __restrict__ hllh16,
                                             u16* __restrict__ xpt) {
  int gx = blockIdx.x;  // 2 (jt) * 4 (ci tile) = 8
  int jt = gx & 1, cit = gx >> 1;
  int i = blockIdx.y, b = blockIdx.z;
  int j0 = jt * 32, ci0 = cit * 32;
  int tx = threadIdx.x & 31, ty = threadIdx.x >> 5;
  __shared__ float sll[32][33], shl[32][33], slh[32][33], shh[32][33];
  if (gx == 0) {
    int pl = 1 + ((threadIdx.x >> 7) << 1);  // planes 1,3: storage col 0
    long off = ((long)(b * 4 + pl) * 4160 + (long)i * 65) * 128 + (threadIdx.x & 127);
    xpt[off] = 0;
  } else if (gx == 1) {
    int pl = (threadIdx.x >> 7) << 1;        // planes 0,2: storage col 64
    long off = ((long)(b * 4 + pl) * 4160 + (long)i * 65 + 64) * 128 + (threadIdx.x & 127);
    xpt[off] = 0;
  }
  const float2* x2 = (const float2*)x;
#pragma unroll
  for (int k = 0; k < 4; ++k) {
    int ci = ty + 8 * k;
    long base = (((long)b * 128 + ci0 + ci) * 128 + 2 * i) * 64 + j0 + tx;
    float2 ab = x2[base];
    float2 cd = x2[base + 64];
    float a = ab.x, bb = ab.y, c = cd.x, d = cd.y;
    sll[ci][tx] = (a + bb + c + d) * 0.5f;
    shl[ci][tx] = (a - bb + c - d) * 0.5f;
    slh[ci][tx] = (a + bb - c - d) * 0.5f;
    shh[ci][tx] = (a - bb - c + d) * 0.5f;
  }
  __syncthreads();
  long tok = (long)b * 4096 + i * 64 + j0;
  int r = threadIdx.x >> 3;         // token col offset 0..31
  int q4 = (threadIdx.x & 7) << 2;  // channel offset 0,4,..,28
  float vll[4], vhl[4], vlh[4], vhh[4];
#pragma unroll
  for (int e = 0; e < 4; ++e) {
    vll[e] = sll[q4 + e][r];
    vhl[e] = shl[q4 + e][r];
    vlh[e] = slh[q4 + e][r];
    vhh[e] = shh[q4 + e][r];
  }
  uint2 u;
  u.x = f2bf_pk(vll[0], vll[1]);
  u.y = f2bf_pk(vll[2], vll[3]);
  *(uint2*)(yL16 + (tok + r) * 128 + ci0 + q4) = u;
  u.x = f2bf_pk(vhl[0], vhl[1]);
  u.y = f2bf_pk(vhl[2], vhl[3]);
  *(uint2*)(hllh16 + (tok + r) * 256 + ci0 + q4) = u;
  u.x = f2bf_pk(vlh[0], vlh[1]);
  u.y = f2bf_pk(vlh[2], vlh[3]);
  *(uint2*)(hllh16 + (tok + r) * 256 + 128 + ci0 + q4) = u;
  {
    int ch = threadIdx.x >> 3;        // channel offset 0..31
    int t4 = (threadIdx.x & 7) << 2;  // token offset 0,4,..,28
    uint2 h;
    h.x = f2bf_pk(shh[ch][t4], shh[ch][t4 + 1]);
    h.y = f2bf_pk(shh[ch][t4 + 2], shh[ch][t4 + 3]);
    *(uint2*)(yHHt16 + (long)(ci0 + ch) * 65536 + tok + t4) = h;
  }
  {
    long rb = (long)(b * 4) * 4160 + (long)i * 65;  // plane0 row base (x128)
    int ci = j0 + r;
    float pA[4], pB[4], pC[4], pD[4];
#pragma unroll
    for (int e = 0; e < 4; ++e) {
      pA[e] = 0.5f * (vll[e] + vhl[e] + vlh[e] + vhh[e]);
      pB[e] = 0.5f * (vll[e] - vhl[e] + vlh[e] - vhh[e]);
      pC[e] = 0.5f * (vll[e] + vhl[e] - vlh[e] - vhh[e]);
      pD[e] = 0.5f * (vll[e] - vhl[e] - vlh[e] + vhh[e]);
    }
    u.x = f2bf_pk(pA[0], pA[1]);
    u.y = f2bf_pk(pA[2], pA[3]);
    *(uint2*)(xpt + (rb + ci) * 128 + ci0 + q4) = u;
    u.x = f2bf_pk(pB[0], pB[1]);
    u.y = f2bf_pk(pB[2], pB[3]);
    *(uint2*)(xpt + (rb + 4160 + ci + 1) * 128 + ci0 + q4) = u;
    u.x = f2bf_pk(pC[0], pC[1]);
    u.y = f2bf_pk(pC[2], pC[3]);
    *(uint2*)(xpt + (rb + 8320 + ci) * 128 + ci0 + q4) = u;
    u.x = f2bf_pk(pD[0], pD[1]);
    u.y = f2bf_pk(pD[2], pD[3]);
    *(uint2*)(xpt + (rb + 12480 + ci + 1) * 128 + ci0 + q4) = u;
  }
}

// ---------------------- weights fp32 -> bf16 (one pass) --------------------
__global__ __launch_bounds__(256) void wcvt8_k(
    const float* __restrict__ a0, const float* __restrict__ a1,
    const float* __restrict__ a2, const float* __restrict__ a3,
    const float* __restrict__ a4, const float* __restrict__ a5,
    const float* __restrict__ a6, const float* __restrict__ a7,
    unsigned* __restrict__ dst, unsigned* __restrict__ zp) {
  if (blockIdx.x >= 768) {
    zp[(blockIdx.x - 768) * 256 + threadIdx.x] = 0;  // 17 blocks = 17408 B
    return;
  }
  int f = blockIdx.x * 256 + threadIdx.x;  // 196608 uints
  int e = 2 * f;
  if (e < 262144) {
    int ch = e >> 13, kg = (e >> 10) & 7, n = (e >> 3) & 127, ke = e & 7;
    int k = ch * 64 + kg * 8 + ke;
    int stg = ch >> 2, sub = ch & 3;
    int kwsel = sub >> 1, chalf = sub & 1;
    int kh = stg >> 1, cp = stg & 1;
    int kw = cp ? (kwsel ? 2 : 0) : (kwsel ? 3 : 1);
    int c = chalf * 64 + (k & 63);
    long si = (((long)n * 128 + c) * 4 + kh) * 4 + kw;
    dst[f] = f2bf_pk(a0[si], a0[si + 16]);  // k+1 -> c+1 -> +16 floats
    return;
  }
  const float* s; int b;
  if (e < 294912)      { s = a1; b = 262144; }
  else if (e < 311296) { s = a2; b = 294912; }
  else if (e < 327680) { s = a3; b = 311296; }
  else if (e < 344064) { s = a4; b = 327680; }
  else if (e < 360448) { s = a5; b = 344064; }
  else if (e < 376832) { s = a6; b = 360448; }
  else                 { s = a7; b = 376832; }
  dst[f] = f2bf_pk(s[e - b], s[e - b + 1]);
}

// --------------------------- unified bf16 GEMM -----------------------------
// (still used for: conv1 1x1, QK softmax-numerator, PV)
template <int AMODE, int EPI>
__global__ __launch_bounds__(256) void gemm16_k(
    const u16* __restrict__ A, long sA, int lda,
    const u16* __restrict__ B, long sB, int ldb,
    u16* __restrict__ C, long sC, int ldc,
    int K, float alpha, const float* __restrict__ bias,
    const u16* __restrict__ aux, const float* __restrict__ sc) {
  __shared__ __align__(16) char smem[32768];
  char* As = smem;
  char* Bs = smem + 16384;
  int z = blockIdx.z;
  int tid = threadIdx.x, lane = tid & 63, w = tid >> 6;
  int wm = w >> 1, wn = w & 1, l15 = lane & 15, l4 = lane >> 4;
  const u16* Ab = A + (long)z * sA + (long)blockIdx.x * 128 * lda;
  const u16* Bb = B + (long)z * sB + (long)blockIdx.y * 128 * ldb;
  const float* scz = (AMODE == 1) ? sc + (long)z * K : nullptr;
  int sm = tid >> 3, skg = tid & 7;
  int sbase = sm * 128 + ((skg ^ (sm & 7)) << 4);
  uint4 pa[4], pb[4];

  auto loadAB = [&](int k0) {
#pragma unroll
    for (int u = 0; u < 4; ++u) {
      pb[u] = *(const uint4*)(Bb + (long)(sm + 32 * u) * ldb + k0 + skg * 8);
      uint4 v = *(const uint4*)(Ab + (long)(sm + 32 * u) * lda + k0 + skg * 8);
      if (AMODE == 1) {
        float4 s0 = *(const float4*)(scz + k0 + skg * 8);
        float4 s1 = *(const float4*)(scz + k0 + skg * 8 + 4);
        v.x = f2bf_pk(bf2f((u16)(v.x & 0xffff)) * s0.x, bf2f((u16)(v.x >> 16)) * s0.y);
        v.y = f2bf_pk(bf2f((u16)(v.y & 0xffff)) * s0.z, bf2f((u16)(v.y >> 16)) * s0.w);
        v.z = f2bf_pk(bf2f((u16)(v.z & 0xffff)) * s1.x, bf2f((u16)(v.z >> 16)) * s1.y);
        v.w = f2bf_pk(bf2f((u16)(v.w & 0xffff)) * s1.z, bf2f((u16)(v.w >> 16)) * s1.w);
      }
      pa[u] = v;
    }
  };

  f32x4 acc[4][4] = {};
  loadAB(0);
  int nch = K >> 6;
  for (int ch = 0; ch < nch; ++ch) {
    __syncthreads();
#pragma unroll
    for (int u = 0; u < 4; ++u) {
      *(uint4*)(As + sbase + u * 4096) = pa[u];
      *(uint4*)(Bs + sbase + u * 4096) = pb[u];
    }
    __syncthreads();
    if (ch + 1 < nch) loadAB((ch + 1) << 6);
#pragma unroll
    for (int s = 0; s < 2; ++s) {
      int ko = (((s << 2) | l4) ^ (l15 & 7)) << 4;
      v8bf af[4], bfr[4];
#pragma unroll
      for (int t = 0; t < 4; ++t) {
        af[t] = *(const v8bf*)(As + (64 * wm + 16 * t + l15) * 128 + ko);
        bfr[t] = *(const v8bf*)(Bs + (64 * wn + 16 * t + l15) * 128 + ko);
      }
#pragma unroll
      for (int mt = 0; mt < 4; ++mt)
#pragma unroll
        for (int nt = 0; nt < 4; ++nt)
          acc[mt][nt] = __builtin_amdgcn_mfma_f32_16x16x32_bf16(af[mt], bfr[nt], acc[mt][nt], 0, 0, 0);
    }
  }
  u16* Cb = C + (long)z * sC;
#pragma unroll
  for (int mt = 0; mt < 4; ++mt) {
#pragma unroll
    for (int nt = 0; nt < 4; ++nt) {
      f32x4 a = acc[mt][nt];
      int n = blockIdx.y * 128 + 64 * wn + 16 * nt + l15;
      float bv = bias ? bias[n] : 0.f;
#pragma unroll
      for (int r = 0; r < 4; ++r) {
        long m = (long)blockIdx.x * 128 + 64 * wm + 16 * mt + 4 * l4 + r;
        float v = a[r] * alpha + bv;
        if (EPI == EPI_EXP) v = __expf(v);
        Cb[m * ldc + n] = f2bf(v);
      }
    }
  }
}

// --------------------------- fused FFN -------------------------------------
// Per 64-token tile (1024 blocks = exactly 4/CU):
//  e1 = gelu(ln1(X)@fc1)        [REGISTERS, packed bf16]
//  A  = gelu(X@div) - e1        [LDS]
//  e2 = gelu(A@fc2)             [REGISTERS]
//  A  = ln3(X); A = gelu(A@fc3a); A = A@fc3b + e2
//  gate = sigmoid(X@act) -> X buffer (X dead after act GEMM)
//  out = lnn(A) * gate.
// Register e-values are written and read by the SAME thread at identical
// fragment (m,n) positions. LDS: X + A = 32 KB. 10 barriers.
// NOTE: no waves_per_eu attribute — allocator must keep 128 VGPRs (r9 lesson:
// the attribute is a MINIMUM; it went to 8 waves/EU = 64 VGPRs and spilled).
__global__ __launch_bounds__(256) void ffn_k(
    const u16* __restrict__ Xg,
    const u16* __restrict__ w_fc1, const u16* __restrict__ w_div,
    const u16* __restrict__ w_fc2, const u16* __restrict__ w_fc3a,
    const u16* __restrict__ w_fc3b, const u16* __restrict__ w_act,
    const float* __restrict__ b_fc1, const float* __restrict__ b_div,
    const float* __restrict__ b_fc2, const float* __restrict__ b_fc3a,
    const float* __restrict__ b_fc3b, const float* __restrict__ b_act,
    const float* __restrict__ ln1g, const float* __restrict__ ln1b,
    const float* __restrict__ ln3g, const float* __restrict__ ln3b,
    const float* __restrict__ lnng, const float* __restrict__ lnnb,
    u16* __restrict__ out) {
  __shared__ __align__(16) char smem[32768];
  char* X = smem;
  char* A = smem + 16384;
  int z = blockIdx.x;
  long t0 = (long)z * 64;
  int tid = threadIdx.x, lane = tid & 63, w = tid >> 6;
  int wm = w >> 1, wn = w & 1, l15 = lane & 15, l4 = lane >> 4;

  // stage X with pre-swizzled global source (LDS dest linear; m173 pattern)
  {
    const u16* src = Xg + t0 * 128;
#pragma unroll
    for (int r = 0; r < 4; ++r) {
      int u = r * 256 + tid;
      int row = u >> 4, cg = u & 15;
      gld_lds16(src + row * 128 + ((cg ^ (row & 7)) << 3),
                X + (r * 256 + w * 64) * 16);
    }
  }

  // GEMM: acc = Asrc(64x128, swizzled LDS) @ Bg(128x128 N-major)^T
  auto gemm = [&](const char* Asrc, const u16* Bg, f32x4 (&acc)[2][4]) {
#pragma unroll
    for (int mt = 0; mt < 2; ++mt)
#pragma unroll
      for (int nt = 0; nt < 4; ++nt) acc[mt][nt] = f32x4{0.f, 0.f, 0.f, 0.f};
#pragma unroll
    for (int s = 0; s < 4; ++s) {
      v8bf af[2], bw[4];
#pragma unroll
      for (int mt = 0; mt < 2; ++mt) {
        int row = 32 * wm + 16 * mt + l15;
        af[mt] = *(const v8bf*)(Asrc + row * 256 + (((s * 4 + l4) ^ (row & 7)) << 4));
      }
#pragma unroll
      for (int nt = 0; nt < 4; ++nt) {
        int rn = 64 * wn + 16 * nt + l15;
        bw[nt] = *(const v8bf*)(Bg + rn * 128 + (s * 4 + l4) * 8);
      }
#pragma unroll
      for (int mt = 0; mt < 2; ++mt)
#pragma unroll
        for (int nt = 0; nt < 4; ++nt)
          acc[mt][nt] = __builtin_amdgcn_mfma_f32_16x16x32_bf16(
              af[mt], bw[nt], acc[mt][nt], 0, 0, 0);
    }
  };

  // register epilogue: er[nt*4 + mt*2 + rp] = packed bf16 pair (r=2rp,2rp+1)
  // mode 0 = gelu, 1 = sigmoid
  auto epi_reg = [&](f32x4 (&acc)[2][4], const float* bias,
                     unsigned (&er)[16], int mode) {
#pragma unroll
    for (int nt = 0; nt < 4; ++nt) {
      float bv = bias[64 * wn + 16 * nt + l15];
#pragma unroll
      for (int mt = 0; mt < 2; ++mt) {
#pragma unroll
        for (int rp = 0; rp < 2; ++rp) {
          float v0 = acc[mt][nt][2 * rp] + bv;
          float v1 = acc[mt][nt][2 * rp + 1] + bv;
          if (mode == 0) { v0 = gelu_f(v0); v1 = gelu_f(v1); }
          else           { v0 = sigmoid_f(v0); v1 = sigmoid_f(v1); }
          er[nt * 4 + mt * 2 + rp] = f2bf_pk(v0, v1);
        }
      }
    }
  };

  // LDS epilogue: mode 0 = gelu(v) - er, 1 = gelu(v), 2 = v + er
  auto epi_lds = [&](f32x4 (&acc)[2][4], const float* bias, char* dst,
                     const unsigned (&er)[16], int mode) {
#pragma unroll
    for (int nt = 0; nt < 4; ++nt) {
      int n = 64 * wn + 16 * nt + l15;
      float bv = bias[n];
#pragma unroll
      for (int mt = 0; mt < 2; ++mt) {
#pragma unroll
        for (int r = 0; r < 4; ++r) {
          int m = 32 * wm + 16 * mt + 4 * l4 + r;
          int off = m * 256 + (((n >> 3) ^ (m & 7)) << 4) + (n & 7) * 2;
          float ev = bf2f((u16)(er[nt * 4 + mt * 2 + (r >> 1)] >> (16 * (r & 1))));
          float v = acc[mt][nt][r] + bv;
          if (mode == 0) v = gelu_f(v) - ev;
          else if (mode == 1) v = gelu_f(v);
          else v += ev;
          *(u16*)(dst + off) = f2bf(v);
        }
      }
    }
  };

  // write packed-register values (epi layout) to LDS
  auto reg_to_lds = [&](const unsigned (&er)[16], char* dst) {
#pragma unroll
    for (int nt = 0; nt < 4; ++nt) {
      int n = 64 * wn + 16 * nt + l15;
#pragma unroll
      for (int mt = 0; mt < 2; ++mt) {
#pragma unroll
        for (int r = 0; r < 4; ++r) {
          int m = 32 * wm + 16 * mt + 4 * l4 + r;
          int off = m * 256 + (((n >> 3) ^ (m & 7)) << 4) + (n & 7) * 2;
          *(u16*)(dst + off) =
              (u16)(er[nt * 4 + mt * 2 + (r >> 1)] >> (16 * (r & 1)));
        }
      }
    }
  };

  // layernorm pass: src (bf16, swizzled LDS) -> dst; 16 rows/wave, 4 lanes/row
  auto lnpass = [&](const char* src, char* dst, const float* g,
                    const float* bt) {
    int row = w * 16 + (lane >> 2), q = lane & 3;
    float v[32];
    float s = 0.f, sq = 0.f;
#pragma unroll
    for (int gi = 0; gi < 4; ++gi) {
      int gr = q * 4 + gi;
      v8bf hv = *(const v8bf*)(src + row * 256 + ((gr ^ (row & 7)) << 4));
#pragma unroll
      for (int e = 0; e < 8; ++e) {
        float f = bf2f(((const u16*)&hv)[e]);
        v[gi * 8 + e] = f;
        s += f;
        sq += f * f;
      }
    }
    s += __shfl_xor(s, 1); sq += __shfl_xor(sq, 1);
    s += __shfl_xor(s, 2); sq += __shfl_xor(sq, 2);
    float mean = s * 0.0078125f;
    float rstd = rsqrtf(sq * 0.0078125f - mean * mean + 1e-5f);
#pragma unroll
    for (int gi = 0; gi < 4; ++gi) {
      int gr = q * 4 + gi;
      int c0 = gr * 8;
      unsigned o[4];
#pragma unroll
      for (int e = 0; e < 4; ++e) {
        float y0 = (v[gi * 8 + 2 * e] - mean) * rstd * g[c0 + 2 * e] + bt[c0 + 2 * e];
        float y1 = (v[gi * 8 + 2 * e + 1] - mean) * rstd * g[c0 + 2 * e + 1] + bt[c0 + 2 * e + 1];
        o[e] = f2bf_pk(y0, y1);
      }
      *(uint4*)(dst + row * 256 + ((gr ^ (row & 7)) << 4)) = *(uint4*)o;
    }
  };

  f32x4 acc[2][4];
  unsigned e1[16], e2[16], sg[16];
  __syncthreads();                               // b1: X staged (drains DMA)
  lnpass(X, A, ln1g, ln1b);
  __syncthreads();                               // b2: A = ln1(X)
  gemm(A, w_fc1, acc);
  epi_reg(acc, b_fc1, e1, 0);                    // e1 = x1 (regs)
  gemm(X, w_div, acc);
  __syncthreads();                               // b3: fc1 reads of A done
  epi_lds(acc, b_div, A, e1, 0);                 // A = gelu(X@div) - x1
  __syncthreads();                               // b4
  gemm(A, w_fc2, acc);
  epi_reg(acc, b_fc2, e2, 0);                    // e2 = x2 (regs)
  __syncthreads();                               // b5: fc2 reads of A done
  lnpass(X, A, ln3g, ln3b);
  __syncthreads();                               // b6: A = ln3(X)
  gemm(A, w_fc3a, acc);
  __syncthreads();                               // b7: fc3a reads done
  epi_lds(acc, b_fc3a, A, e1, 1);                // A = h = gelu(.)
  __syncthreads();                               // b8
  gemm(X, w_act, acc);
  epi_reg(acc, b_act, sg, 1);                    // sg = gate (regs)
  gemm(A, w_fc3b, acc);
  __syncthreads();                               // b9: reads of A and X done
  epi_lds(acc, b_fc3b, A, e2, 2);                // A = x2 + x3
  reg_to_lds(sg, X);                             // X = gate
  __syncthreads();                               // b10

  // final: out = lnn(A) * gate(X), written straight to global
  {
    int row = w * 16 + (lane >> 2), q = lane & 3;
    float v[32];
    float s = 0.f, sq = 0.f;
#pragma unroll
    for (int gi = 0; gi < 4; ++gi) {
      int gr = q * 4 + gi;
      v8bf hv = *(const v8bf*)(A + row * 256 + ((gr ^ (row & 7)) << 4));
#pragma unroll
      for (int e = 0; e < 8; ++e) {
        float f = bf2f(((const u16*)&hv)[e]);
        v[gi * 8 + e] = f;
        s += f;
        sq += f * f;
      }
    }
    s += __shfl_xor(s, 1); sq += __shfl_xor(sq, 1);
    s += __shfl_xor(s, 2); sq += __shfl_xor(sq, 2);
    float mean = s * 0.0078125f;
    float rstd = rsqrtf(sq * 0.0078125f - mean * mean + 1e-5f);
    u16* og = out + (t0 + row) * 128;
#pragma unroll
    for (int gi = 0; gi < 4; ++gi) {
      int gr = q * 4 + gi;
      int c0 = gr * 8;
      v8bf gv = *(const v8bf*)(X + row * 256 + ((gr ^ (row & 7)) << 4));
      unsigned o[4];
#pragma unroll
      for (int e = 0; e < 4; ++e) {
        float y0 = ((v[gi * 8 + 2 * e] - mean) * rstd * lnng[c0 + 2 * e] + lnnb[c0 + 2 * e]) *
                   bf2f(((const u16*)&gv)[2 * e]);
        float y1 = ((v[gi * 8 + 2 * e + 1] - mean) * rstd * lnng[c0 + 2 * e + 1] + lnnb[c0 + 2 * e + 1]) *
                   bf2f(((const u16*)&gv)[2 * e + 1]);
        o[e] = f2bf_pk(y0, y1);
      }
      *(uint4*)(og + c0) = *(uint4*)o;
    }
  }
}

// ------------- conv 4x4 s2 p1: polyphase implicit GEMM (bf16) --------------
__global__ __launch_bounds__(256) __attribute__((amdgpu_waves_per_eu(4)))
void conv4g_k(const u16* __restrict__ xpt, const u16* __restrict__ wb,
              const float* __restrict__ bias, const u16* __restrict__ zp,
              u16* __restrict__ dw16) {
  __shared__ __align__(16) char smem[33280];  // 2 x 16640 A buffers
  char* As = smem;
  int raw = blockIdx.x;
  int swz = (raw & 7) * 128 + (raw >> 3);
  int oi = swz & 63, b = swz >> 6;
  int tid = threadIdx.x, lane = tid & 63, w = tid >> 6;
  int wm = w >> 1, wn = w & 1, l15 = lane & 15, l4 = lane >> 4;
  f32x4 acc[2][4] = {};

  auto issueA = [&](int stg2, int bsel) {
    int kh = stg2 >> 1, cp2 = stg2 & 1;
    int roff = (kh == 0) ? -1 : (kh == 3) ? 1 : 0;
    int ri = oi + roff;
    int ph = (((kh + 1) & 1) << 1) | cp2;
    const u16* rowb = ((unsigned)ri < 64u)
        ? xpt + ((long)(b * 4 + ph) * 4160 + (long)ri * 65) * 128
        : zp;
    char* lb = As + bsel * 16640 + w * 1024;
#pragma unroll
    for (int i = 0; i < 4; ++i) {
      int d = i * 4096 + w * 1024 + lane * 16;
      int slot = d >> 8, cg = (d >> 4) & 15;
      gld_lds16(rowb + slot * 128 + ((cg ^ ((slot - cp2) & 7)) << 3),
                lb + i * 4096);
    }
    if (tid < 16) {
      gld_lds16(rowb + 64 * 128 + ((lane ^ ((64 - cp2) & 7)) << 3),
                As + bsel * 16640 + 16384);
    }
  };

  issueA(0, 0);
  for (int stg = 0; stg < 8; ++stg) {
    __syncthreads();
    if (stg < 7) issueA(stg + 1, (stg + 1) & 1);
    const char* Ab = As + (stg & 1) * 16640;
    int cp2 = stg & 1;
#pragma unroll
    for (int sub = 0; sub < 4; ++sub) {
      int chunk = stg * 4 + sub;
      const int kwsel = sub >> 1, chalf = sub & 1;
#pragma unroll
      for (int s = 0; s < 2; ++s) {
        v8bf bw[4], af[2];
#pragma unroll
        for (int nt = 0; nt < 4; ++nt) {
          int row = 64 * wn + 16 * nt + l15;
          bw[nt] = *(const v8bf*)(wb + ((long)(chunk * 8 + s * 4 + l4) * 128 + row) * 8);
        }
#pragma unroll
        for (int mt = 0; mt < 2; ++mt) {
          int slot = 32 * wm + 16 * mt + l15 + kwsel;
          int cg = chalf * 8 + s * 4 + l4;
          af[mt] = *(const v8bf*)(Ab + slot * 256 + ((cg ^ ((slot - cp2) & 7)) << 4));
        }
#pragma unroll
        for (int mt = 0; mt < 2; ++mt)
#pragma unroll
          for (int nt = 0; nt < 4; ++nt)
            acc[mt][nt] = __builtin_amdgcn_mfma_f32_16x16x32_bf16(
                af[mt], bw[nt], acc[mt][nt], 0, 0, 0);
      }
    }
  }
  __syncthreads();
  float* buf = (float*)(smem + w * 2176);  // 16 x 34 f32 per wave
  long obase = ((long)b * 128) * 4096 + oi * 64;
#pragma unroll
  for (int cg = 0; cg < 4; ++cg) {
    int co = 64 * wn + 16 * cg + l15;
    float bv = bias[co];
#pragma unroll
    for (int mt = 0; mt < 2; ++mt) {
      f32x4 a = acc[mt][cg];
#pragma unroll
      for (int r = 0; r < 4; ++r)
        buf[l15 * 34 + 16 * mt + 4 * l4 + r] = fmaxf(a[r] + bv, 0.f);
    }
    __syncthreads();
#pragma unroll
    for (int it = 0; it < 8; ++it) {
      int row = it * 2 + (lane >> 5);
      int mcol = lane & 31;
      int coz = 64 * wn + 16 * cg + row;
      dw16[obase + (long)coz * 4096 + 32 * wm + mcol] = f2bf(buf[row * 34 + mcol]);
    }
    __syncthreads();
  }
}

// --------------- attention column normalizer: sc = 1/sum_q E ---------------
__global__ __launch_bounds__(256) void ssum_k(const u16* __restrict__ E,
                                              float* __restrict__ sc) {
  int z = blockIdx.y;
  int k = blockIdx.x * 256 + threadIdx.x;
  const u16* Eb = E + (long)z * 262144 + k;
  float s = 0.f;
#pragma unroll 8
  for (int q = 0; q < 512; ++q) s += bf2f(Eb[(long)q * 512]);
  sc[(long)z * 512 + k] = 1.f / s;
}

// ------------------------------ combine ------------------------------------
__global__ __launch_bounds__(256) void combine_k(const u16* __restrict__ attf,
                                                 const u16* __restrict__ yt,
                                                 const u16* __restrict__ dw16,
                                                 const float* __restrict__ x,
                                                 float* __restrict__ out) {
  int gx = blockIdx.x;  // 2 (jt) * 4 (cot) = 8
  int jt = gx & 1, cot = gx >> 1;
  int i = blockIdx.y, b = blockIdx.z;
  int j0 = jt * 32, co0 = cot * 32;
  int tx = threadIdx.x & 31, ty = threadIdx.x >> 5;
  __shared__ float sa[32][33], sy[32][33];
  long tokbase = (long)b * 4096 + i * 64 + j0;
#pragma unroll
  for (int k = 0; k < 4; ++k) {
    int row = ty + 8 * k;
    long idx = (tokbase + row) * 128 + co0 + tx;
    sa[row][tx] = bf2f(attf[idx]);
    sy[row][tx] = bf2f(yt[idx]);
  }
  __syncthreads();
  float py = (float)(i * 127) / 63.0f;
  int y0 = (int)py;
  int y1 = min(y0 + 1, 127);
  float wy = py - (float)y0;
  int j = j0 + tx;
  float px = (float)(j * 127) / 63.0f;
  int x0 = (int)px;
  int x1 = min(x0 + 1, 127);
  float wx = px - (float)x0;
#pragma unroll
  for (int k = 0; k < 4; ++k) {
    int co = co0 + ty + 8 * k;
    const float* xb = x + (((long)b * 128 + co) * 128) * 128;
    float r0 = xb[y0 * 128 + x0] * (1.f - wx) + xb[y0 * 128 + x1] * wx;
    float r1 = xb[y1 * 128 + x0] * (1.f - wx) + xb[y1 * 128 + x1] * wx;
    float d2 = r0 * (1.f - wy) + r1 * wy;
    long oidx = (((long)b * 128 + co) * 64 + i) * 64 + j;
    float dwv = bf2f(dw16[oidx]);
    out[oidx] = sa[tx][ty + 8 * k] * (d2 - dwv) + sy[tx][ty + 8 * k];
  }
}

// ---------------------------------------------------------------------------
extern "C" void kernel_launch(void* const* d_in, const int* in_sizes, int n_in,
                              void* d_out, int out_size, void* d_ws, size_t ws_size,
                              hipStream_t stream) {
  const float* x = (const float*)d_in[0];
  const float* w1 = (const float*)d_in[1];
  const float* b1 = (const float*)d_in[2];
  const float* l1w = (const float*)d_in[3];
  const float* l1b = (const float*)d_in[4];
  const float* ln1g = (const float*)d_in[5];
  const float* ln1b = (const float*)d_in[6];
  const float* fc1w = (const float*)d_in[7];
  const float* fc1b = (const float*)d_in[8];
  const float* divw = (const float*)d_in[9];
  const float* divb = (const float*)d_in[10];
  const float* fc2w = (const float*)d_in[11];
  const float* fc2b = (const float*)d_in[12];
  const float* ln3g = (const float*)d_in[13];
  const float* ln3b = (const float*)d_in[14];
  const float* fc3aw = (const float*)d_in[15];
  const float* fc3ab = (const float*)d_in[16];
  const float* fc3bw = (const float*)d_in[17];
  const float* fc3bb = (const float*)d_in[18];
  const float* lnng = (const float*)d_in[19];
  const float* lnnb = (const float*)d_in[20];
  const float* actw = (const float*)d_in[21];
  const float* actb = (const float*)d_in[22];

  char* W = (char*)d_ws;
  u16* yL16 = (u16*)(W);
  u16* hllh16 = (u16*)(W + 16777216L);
  u16* yHHt16 = (u16*)(W + 50331648L);
  u16* y16 = (u16*)(W + 67108864L);
  u16* S16 = (u16*)(W + 83886080L);
  u16* attO16 = (u16*)(W + 150994944L);
  u16* dw16 = (u16*)(W + 167772160L);
  u16* t2 = (u16*)(W + 201326592L);
  float* sc = (float*)(W + 251658240L);
  u16* wall = (u16*)(W + 251920384L);
  u16* l1wb = wall;
  u16* w1b = wall + 262144;
  u16* fc1b16 = wall + 294912;
  u16* divb16 = wall + 311296;
  u16* fc2b16 = wall + 327680;
  u16* fc3ab16 = wall + 344064;
  u16* fc3bb16 = wall + 360448;
  u16* actb16 = wall + 376832;
  u16* xpt16 = S16;  // polyphase planes live in S16 region until QK GEMM
  u16* zp16 = (u16*)(W + 152043520L);  // 17408-B zero page (row-OOB reads)

  dim3 blk(256);
  const float qk_scale = 0.35355339059327373f;  // 8^-0.5

  wcvt8_k<<<dim3(785), blk, 0, stream>>>(l1w, w1, fc1w, divw, fc2w, fc3aw,
                                         fc3bw, actw, (unsigned*)wall,
                                         (unsigned*)zp16);
  // 1. DWT + transpose (bf16 outputs incl. yHH^T and padded polyphase planes)
  pre_k<<<dim3(8, 64, 16), blk, 0, stream>>>(x, yL16, yHHt16, hllh16, xpt16);
  // 2. conv1 (1x1, 256->128): y16 = hllh @ w1^T + b1
  gemm16_k<0, EPI_NONE><<<dim3(512, 1, 1), blk, 0, stream>>>(
      hllh16, 0, 256, w1b, 0, 256, y16, 0, 128, 256, 1.f, b1, nullptr, nullptr);
  // 3. conv4x4 stride2 + relu (DMA-staged polyphase implicit GEMM)
  conv4g_k<<<dim3(1024), blk, 0, stream>>>(xpt16, l1wb, l1b, zp16, dw16);
  // 4. E = exp(scale * yL @ y^T)  (softmax numerator; overwrites xpt region)
  gemm16_k<0, EPI_EXP><<<dim3(4, 4, 128), blk, 0, stream>>>(
      yL16, 65536, 128, y16, 65536, 128, S16, 262144, 512, 128, qk_scale,
      nullptr, nullptr, nullptr);
  // 5. sc_k = 1 / sum_q E
  ssum_k<<<dim3(2, 128), blk, 0, stream>>>(S16, sc);
  // 6. attO = (E * sc) @ yHH   (scale folded into A-loader, B = yHH^T rows)
  gemm16_k<1, EPI_NONE><<<dim3(4, 1, 128), blk, 0, stream>>>(
      S16, 262144, 512, yHHt16, 512, 65536, attO16, 65536, 128, 512, 1.f,
      nullptr, nullptr, sc);
  // 7. fused FFN: attO -> t2
  ffn_k<<<dim3(1024), blk, 0, stream>>>(
      attO16, fc1b16, divb16, fc2b16, fc3ab16, fc3bb16, actb16,
      fc1b, divb, fc2b, fc3ab, fc3bb, actb,
      ln1g, ln1b, ln3g, ln3b, lnng, lnnb, t2);
  // 8. combine: out = attf * (resize(x) - dw) + y
  combine_k<<<dim3(8, 64, 16), blk, 0, stream>>>(t2, y16, dw16, x, (float*)d_out);
}